// Round 10
// baseline (319.402 us; speedup 1.0000x reference)
//
#include <hip/hip_runtime.h>
#include <hip/hip_bf16.h>

#define B_SZ 4
#define T_SEQ 1024
#define DM 128
#define ED_ 256
#define NS 64
#define CLEN 64
#define NCHUNK 16

// workspace layout (float elements). Total = 6,389,760 floats = 25.6 MB.
#define OFF_Z      0u         /* 524288  f32  z (residual, read by K6)            */
#define OFF_BC     524288u    /* 524288  f32  interleaved [bt][n][{B,C}]          */
#define OFF_XSR    1048576u   /* 1048576 f32  conv input (k2f->k4b)               */
#define OFF_ZG     2097152u   /* 1048576 f32  gate (read by K6)                   */
#define OFF_XS     3145728u   /* 1048576 f32  conv+silu output [bt][e]            */
#define OFF_WC     4194304u   /* 98304   f32  combined weight (k2f->k4b)          */
#define OFF_YR     4292608u   /* 1048576 f32  raw scan dot p, [bt][e] (k5->k6)    */
#define OFF_DELTA  5341184u   /* 1048576 f32  softplus delta [bt][e]              */

__device__ __forceinline__ float sigmoidf_(float x){ return 1.f/(1.f+__expf(-x)); }
__device__ __forceinline__ float rlane(float v, int l){
  return __int_as_float(__builtin_amdgcn_readlane(__float_as_int(v), l));
}

// Single-instruction DPP add (canonical GFX9 cross-lane reduce step).
#define DPPADD(p, mods) asm("v_add_f32 %0, %0, %0 " mods : "+v"(p))
// Full 6-step wave64 sum; result in lane 63.
#define DPP_L1(p) DPPADD(p, "row_shr:1 bound_ctrl:0")
#define DPP_L2(p) DPPADD(p, "row_shr:2 bound_ctrl:0")
#define DPP_L3(p) DPPADD(p, "row_shr:4 bank_mask:0xe")
#define DPP_L4(p) DPPADD(p, "row_shr:8 bank_mask:0xc")
#define DPP_L5(p) DPPADD(p, "row_bcast:15 row_mask:0xa")
#define DPP_L6(p) DPPADD(p, "row_bcast:31 row_mask:0xc")

// K2f: blocks 0..511: fused [z = zseq+aux@auxW.T+auxb ; zn=RMSNorm(z)*rms_w] -> LDS,
//      then xz = zn @ in_proj_W.T -> xsr | zg. blocks 512..895: build Wc.
__global__ __launch_bounds__(256) void k2_fused(const float* zseq, const float* aux, const float* auxW,
                                                const float* auxb, const float* rmsw, const float* W,
                                                const float* xprojW, const float* dtW,
                                                float* z, float* xsr, float* zg, float* Wc){
  if (blockIdx.x >= 512){
    int r = blockIdx.x - 512; int k = threadIdx.x;
    float v;
    if (r < 256){
      v = 0.f;
      #pragma unroll
      for (int j=0;j<8;j++) v += dtW[r*8+j] * xprojW[j*256+k];
    } else {
      v = xprojW[(8 + r-256)*256 + k];
    }
    Wc[r*256+k] = v;
    return;
  }
  __shared__ float at[128][8];
  int bt0 = blockIdx.x*8; int tid = threadIdx.x;
  {
    int r = tid>>5, l = tid&31;
    int bt = bt0 + r;
    float a0 = aux[bt*3+0], a1 = aux[bt*3+1], a2 = aux[bt*3+2];
    float zv[4]; float ssq = 0.f;
    #pragma unroll
    for (int j=0;j<4;j++){
      int d = l + 32*j;
      float v = zseq[bt*DM+d] + a0*auxW[d*3+0] + a1*auxW[d*3+1] + a2*auxW[d*3+2] + auxb[d];
      zv[j] = v; ssq += v*v;
    }
    #pragma unroll
    for (int m=16;m>=1;m>>=1) ssq += __shfl_xor(ssq, m);
    float rinv = rsqrtf(ssq*(1.f/DM) + 1e-5f);
    #pragma unroll
    for (int j=0;j<4;j++){
      int d = l + 32*j;
      z[bt*DM+d] = zv[j];
      at[d][r] = zv[j]*rinv*rmsw[d];
    }
  }
  __syncthreads();
  float acc0[8], acc1[8];
  #pragma unroll
  for (int r=0;r<8;r++){ acc0[r]=0.f; acc1[r]=0.f; }
  int c0 = tid, c1 = tid+256;
  for (int k=0;k<128;k+=4){
    float4 w0v = *(const float4*)(W + c0*128 + k);
    float4 w1v = *(const float4*)(W + c1*128 + k);
    float w0[4] = {w0v.x, w0v.y, w0v.z, w0v.w};
    float w1[4] = {w1v.x, w1v.y, w1v.z, w1v.w};
    #pragma unroll
    for (int kk=0;kk<4;kk++){
      float a[8];
      *(float4*)&a[0] = *(const float4*)&at[k+kk][0];
      *(float4*)&a[4] = *(const float4*)&at[k+kk][4];
      #pragma unroll
      for (int r=0;r<8;r++){ acc0[r] = fmaf(a[r], w0[kk], acc0[r]); acc1[r] = fmaf(a[r], w1[kk], acc1[r]); }
    }
  }
  #pragma unroll
  for (int r=0;r<8;r++){
    int bt = bt0+r;
    xsr[bt*ED_ + c0] = acc0[r];
    zg [bt*ED_ + c0] = acc1[r];
  }
}

// K4b: staging computes conv(k=4)+bias+SiLU from xsr into LDS (and coalesced xs),
// then GEMM vs Wc: cols 0..255 -> delta=softplus(.+dt_b) [bt][e] coalesced;
// cols 256..319 -> B into BC[bt][n][0]; cols 320..383 -> C into BC[bt][n][1].
__global__ __launch_bounds__(384) void k4b_xproj(const float* xsr, const float* convW, const float* convb,
                                                 const float* Wc, const float* dtb,
                                                 float* xs, float* delta, float* BC){
  __shared__ float at[256][8];
  int bt0 = blockIdx.x*8; int tid = threadIdx.x;
  for (int i=tid;i<2048;i+=384){
    int r=i>>8,k=i&255; int bt=bt0+r; int t = bt & (T_SEQ-1);
    float4 wv = *(const float4*)(convW + k*4);
    float s = convb[k];
    if (t>=3) s += xsr[(bt-3)*ED_+k]*wv.x;
    if (t>=2) s += xsr[(bt-2)*ED_+k]*wv.y;
    if (t>=1) s += xsr[(bt-1)*ED_+k]*wv.z;
    s += xsr[bt*ED_+k]*wv.w;
    float v = s * sigmoidf_(s);
    at[k][r] = v;
    xs[bt*ED_+k] = v;
  }
  __syncthreads();
  float acc[8];
  #pragma unroll
  for (int r=0;r<8;r++) acc[r]=0.f;
  int c = tid;
  for (int k=0;k<256;k+=4){
    float4 wv = *(const float4*)(Wc + c*256 + k);
    float w[4] = {wv.x, wv.y, wv.z, wv.w};
    #pragma unroll
    for (int kk=0;kk<4;kk++){
      float a[8];
      *(float4*)&a[0] = *(const float4*)&at[k+kk][0];
      *(float4*)&a[4] = *(const float4*)&at[k+kk][4];
      #pragma unroll
      for (int r=0;r<8;r++) acc[r] = fmaf(a[r], w[kk], acc[r]);
    }
  }
  if (c < 256){
    float bc = dtb[c];
    #pragma unroll
    for (int r=0;r<8;r++){
      float x = acc[r] + bc;
      delta[(bt0+r)*ED_ + c] = (x > 20.f) ? x : log1pf(__expf(x));
    }
  } else if (c < 320){
    int n = c-256;
    #pragma unroll
    for (int r=0;r<8;r++) BC[((size_t)(bt0+r)*NS + n)*2]     = acc[r];
  } else {
    int n = c-320;
    #pragma unroll
    for (int r=0;r<8;r++) BC[((size_t)(bt0+r)*NS + n)*2 + 1] = acc[r];
  }
}

// K5: fused two-phase scan. Block = (b,e), 1024 threads = 16 waves = 16 chunks.
// Phase 1: wave c local-scans chunk c (seed 0), S and sd(=sum delta) -> LDS.
// Phase 2: wave c folds chunks <c from LDS into seed, re-scans with C-dot,
// lane 63 stores raw p[t]. delta/x streams live lane-distributed (lane t of the
// chunk) and are broadcast per-t via v_readlane (constant lanes, full unroll).
// XCD swizzle: block i -> XCD i%8; each XCD owns a 32-wide e-range.
__global__ __launch_bounds__(1024,8) void k5_fused(const float* __restrict__ delta, const float* __restrict__ xs,
                                                    const float* __restrict__ BC, const float* __restrict__ Alog,
                                                    float* __restrict__ yr){
  __shared__ float ldsS[NCHUNK*NS];
  __shared__ float ldsSd[NCHUNK];
  int i = blockIdx.x;
  int c = threadIdx.x >> 6, n = threadIdx.x & 63;
  int j = i >> 3;
  int b = j & 3;
  int e = (i&7)*32 + (j>>2);
  float A = -__expf(Alog[e*NS+n]);
  int base = b*T_SEQ + c*CLEN;
  const float* pd = delta + (size_t)base*ED_ + e;
  const float* px = xs    + (size_t)base*ED_ + e;
  const float2* pbc = (const float2*)BC + (size_t)base*NS + n;
  float*        py  = yr + (size_t)base*ED_ + e;
  float dl_lane = pd[n*ED_];          // lane t -> delta[chunk t]
  float xx_lane = px[n*ED_];          // lane t -> x[chunk t]
  float dlxx = dl_lane * xx_lane;
  bool last = (n==63);

  // ---- phase 1: local scan, seed 0 ----
  float h = 0.f;
  #pragma unroll
  for (int t=0; t<CLEN; t+=8){
    float bx[8];
    #pragma unroll
    for (int j2=0;j2<8;j2++) bx[j2] = pbc[(t+j2)*NS].x;
    #pragma unroll
    for (int j2=0;j2<8;j2++){
      float sdl = rlane(dl_lane, t+j2);
      float sq  = rlane(dlxx,   t+j2);
      float a = __expf(sdl*A);
      h = fmaf(a, h, sq*bx[j2]);
    }
  }
  float sd = dl_lane;
  DPP_L1(sd); DPP_L2(sd); DPP_L3(sd); DPP_L4(sd); DPP_L5(sd); DPP_L6(sd);
  ldsS[c*NS+n] = h;
  if (last) ldsSd[c] = sd;
  __syncthreads();

  // ---- phase 2: fold prefix chunks, then scan with C-dot ----
  h = 0.f;
  for (int cc=0; cc<c; ++cc){         // c is wave-uniform -> no divergence
    float p = __expf(ldsSd[cc]*A);
    h = fmaf(p, h, ldsS[cc*NS+n]);
  }
  #pragma unroll
  for (int t=0; t<CLEN; t+=8){
    float2 bc[8];
    #pragma unroll
    for (int j2=0;j2<8;j2++) bc[j2] = pbc[(t+j2)*NS];
    float pp[8];
    #pragma unroll
    for (int j2=0;j2<8;j2++){
      float sdl = rlane(dl_lane, t+j2);
      float sq  = rlane(dlxx,   t+j2);
      float a = __expf(sdl*A);
      h = fmaf(a, h, sq*bc[j2].x);
      pp[j2] = h*bc[j2].y;
    }
    #pragma unroll
    for (int j2=0;j2<8;j2++) DPP_L1(pp[j2]);
    #pragma unroll
    for (int j2=0;j2<8;j2++) DPP_L2(pp[j2]);
    #pragma unroll
    for (int j2=0;j2<8;j2++) DPP_L3(pp[j2]);
    #pragma unroll
    for (int j2=0;j2<8;j2++) DPP_L4(pp[j2]);
    #pragma unroll
    for (int j2=0;j2<8;j2++) DPP_L5(pp[j2]);
    #pragma unroll
    for (int j2=0;j2<8;j2++) DPP_L6(pp[j2]);
    if (last){
      #pragma unroll
      for (int j2=0;j2<8;j2++) py[(t+j2)*ED_] = pp[j2];
    }
  }
}

// K6: y = (yr + D*xs)*silu(zg);  out = LayerNorm(y @ out_proj_W.T + 2*z)*ln_w + ln_b
__global__ __launch_bounds__(256) void k6_out(const float* yr, const float* xs, const float* zg,
                                               const float* Dp, const float* W, const float* z,
                                               const float* lnw, const float* lnb, float* out){
  __shared__ float yt[256][8];
  __shared__ float psum[4][4], psq[4][4];
  int bt0 = blockIdx.x*8; int tid = threadIdx.x;
  int d = tid & 127, gdx = tid>>7;
  for (int i=tid;i<2048;i+=256){
    int r=i>>8,k=i&255; int bt=bt0+r;
    float zgv = zg[bt*ED_ + k];
    float yv  = yr[bt*ED_ + k] + Dp[k]*xs[bt*ED_ + k];
    yt[k][r] = yv * zgv * sigmoidf_(zgv);
  }
  __syncthreads();
  float acc[4] = {0.f,0.f,0.f,0.f};
  for (int k=0;k<256;k+=4){
    float4 wv = *(const float4*)(W + d*256 + k);
    float w[4] = {wv.x, wv.y, wv.z, wv.w};
    #pragma unroll
    for (int kk=0;kk<4;kk++){
      float4 q = *(const float4*)&yt[k+kk][gdx*4];
      acc[0] = fmaf(q.x, w[kk], acc[0]);
      acc[1] = fmaf(q.y, w[kk], acc[1]);
      acc[2] = fmaf(q.z, w[kk], acc[2]);
      acc[3] = fmaf(q.w, w[kk], acc[3]);
    }
  }
  float val[4];
  #pragma unroll
  for (int j=0;j<4;j++){
    int bt = bt0 + gdx*4 + j;
    val[j] = acc[j] + 2.f*z[bt*DM + d];
  }
  int w_id = tid>>6;
  #pragma unroll
  for (int j=0;j<4;j++){
    float s = val[j], q = val[j]*val[j];
    #pragma unroll
    for (int off=32; off>=1; off>>=1){ s += __shfl_down(s, off); q += __shfl_down(q, off); }
    if ((tid&63)==0){ psum[w_id][j]=s; psq[w_id][j]=q; }
  }
  __syncthreads();
  float lw = lnw[d], lb = lnb[d];
  #pragma unroll
  for (int j=0;j<4;j++){
    int bt = bt0 + gdx*4 + j;
    float sum = psum[gdx*2][j] + psum[gdx*2+1][j];
    float sq  = psq [gdx*2][j] + psq [gdx*2+1][j];
    float mu  = sum*(1.f/DM);
    float var = sq*(1.f/DM) - mu*mu;
    float inv = rsqrtf(var + 1e-5f);
    out[bt*DM + d] = (val[j]-mu)*inv*lw + lb;
  }
}

extern "C" void kernel_launch(void* const* d_in, const int* in_sizes, int n_in,
                              void* d_out, int out_size, void* d_ws, size_t ws_size,
                              hipStream_t stream){
  const float* zseq = (const float*)d_in[0];
  const float* aux  = (const float*)d_in[1];
  const float* auxW = (const float*)d_in[2];
  const float* auxb = (const float*)d_in[3];
  const float* lnw  = (const float*)d_in[4];
  const float* lnb  = (const float*)d_in[5];
  const float* rmsw = (const float*)d_in[6];
  const float* inW  = (const float*)d_in[7];
  const float* convW= (const float*)d_in[8];
  const float* convb= (const float*)d_in[9];
  const float* xpW  = (const float*)d_in[10];
  const float* dtW  = (const float*)d_in[11];
  const float* dtb  = (const float*)d_in[12];
  const float* Alog = (const float*)d_in[13];
  const float* Dp   = (const float*)d_in[14];
  const float* outW = (const float*)d_in[15];
  float* out = (float*)d_out;
  float* ws = (float*)d_ws;

  float* z   = ws+OFF_Z;
  float* BC  = ws+OFF_BC;
  float* xsr = ws+OFF_XSR;  float* zg = ws+OFF_ZG;   float* xs = ws+OFF_XS;
  float* Wc  = ws+OFF_WC;
  float* yr  = ws+OFF_YR;   float* dl = ws+OFF_DELTA;

  k2_fused <<<896,256,0,stream>>>(zseq,aux,auxW,auxb,rmsw,inW,xpW,dtW,z,xsr,zg,Wc);
  k4b_xproj<<<512,384,0,stream>>>(xsr,convW,convb,Wc,dtb,xs,dl,BC);
  k5_fused <<<1024,1024,0,stream>>>(dl,xs,BC,Alog,yr);
  k6_out   <<<512,256,0,stream>>>(yr,xs,zg,Dp,outW,z,lnw,lnb,out);
}

// Round 11
// 244.904 us; speedup vs baseline: 1.3042x; 1.3042x over previous
//
#include <hip/hip_runtime.h>
#include <hip/hip_bf16.h>

#define B_SZ 4
#define T_SEQ 1024
#define DM 128
#define ED_ 256
#define NS 64
#define CLEN 64
#define NCHUNK 16

// workspace layout (float elements). Total = 6,389,760 floats = 25.6 MB.
// Aliasing: S overwrites xsr (dead after k4b); sd overwrites Wc (dead after k4b).
#define OFF_Z      0u         /* 524288  f32  z (residual, read by K6)            */
#define OFF_BC     524288u    /* 524288  f32  interleaved [bt][n][{B,C}]          */
#define OFF_XSR    1048576u   /* 1048576 f32  conv input (k2f->k4b); later S      */
#define OFF_ZG     2097152u   /* 1048576 f32  gate (read by K6)                   */
#define OFF_XS     3145728u   /* 1048576 f32  conv+silu output [bt][e]            */
#define OFF_WC     4194304u   /* 98304   f32  combined weight (k2f->k4b); later sd*/
#define OFF_YR     4292608u   /* 1048576 f32  raw scan dot p, [bt][e] (k5c->k6)   */
#define OFF_DELTA  5341184u   /* 1048576 f32  softplus delta [bt][e]              */
#define OFF_S      (OFF_XSR)
#define OFF_SD     (OFF_WC)

__device__ __forceinline__ float sigmoidf_(float x){ return 1.f/(1.f+__expf(-x)); }
__device__ __forceinline__ float rlane(float v, int l){
  return __int_as_float(__builtin_amdgcn_readlane(__float_as_int(v), l));
}

// Single-instruction DPP add (canonical GFX9 cross-lane reduce; correctness
// verified in R10 — absmax identical). Result of the 6-step sequence in lane 63.
#define DPPADD(p, mods) asm("v_add_f32 %0, %0, %0 " mods : "+v"(p))
#define DPP_L1(p) DPPADD(p, "row_shr:1 bound_ctrl:0")
#define DPP_L2(p) DPPADD(p, "row_shr:2 bound_ctrl:0")
#define DPP_L3(p) DPPADD(p, "row_shr:4 bank_mask:0xe")
#define DPP_L4(p) DPPADD(p, "row_shr:8 bank_mask:0xc")
#define DPP_L5(p) DPPADD(p, "row_bcast:15 row_mask:0xa")
#define DPP_L6(p) DPPADD(p, "row_bcast:31 row_mask:0xc")

// (b,e,c) mapping for k5a/k5c. 4096 blocks, 4 waves each. XCD-aware: block
// i -> XCD i%8; each XCD owns 2 of the 16 e-line groups.
__device__ __forceinline__ void scan_map(int i, int w, int& b, int& c, int& e){
  int x = i & 7;
  int j = i >> 3;
  int lg = x*2 + (j & 1);
  int j2 = j >> 1;           // 0..255
  b = j2 & 3;
  c = (j2 >> 2) & 15;
  int q = j2 >> 6;           // 0..3
  e = lg*16 + q*4 + w;
}

// K2f: blocks 0..511: fused [z = zseq+aux@auxW.T+auxb ; zn=RMSNorm(z)*rms_w] -> LDS,
//      then xz = zn @ in_proj_W.T -> xsr | zg. blocks 512..895: build Wc.
__global__ __launch_bounds__(256) void k2_fused(const float* zseq, const float* aux, const float* auxW,
                                                const float* auxb, const float* rmsw, const float* W,
                                                const float* xprojW, const float* dtW,
                                                float* z, float* xsr, float* zg, float* Wc){
  if (blockIdx.x >= 512){
    int r = blockIdx.x - 512; int k = threadIdx.x;
    float v;
    if (r < 256){
      v = 0.f;
      #pragma unroll
      for (int j=0;j<8;j++) v += dtW[r*8+j] * xprojW[j*256+k];
    } else {
      v = xprojW[(8 + r-256)*256 + k];
    }
    Wc[r*256+k] = v;
    return;
  }
  __shared__ float at[128][8];
  int bt0 = blockIdx.x*8; int tid = threadIdx.x;
  {
    int r = tid>>5, l = tid&31;
    int bt = bt0 + r;
    float a0 = aux[bt*3+0], a1 = aux[bt*3+1], a2 = aux[bt*3+2];
    float zv[4]; float ssq = 0.f;
    #pragma unroll
    for (int j=0;j<4;j++){
      int d = l + 32*j;
      float v = zseq[bt*DM+d] + a0*auxW[d*3+0] + a1*auxW[d*3+1] + a2*auxW[d*3+2] + auxb[d];
      zv[j] = v; ssq += v*v;
    }
    #pragma unroll
    for (int m=16;m>=1;m>>=1) ssq += __shfl_xor(ssq, m);
    float rinv = rsqrtf(ssq*(1.f/DM) + 1e-5f);
    #pragma unroll
    for (int j=0;j<4;j++){
      int d = l + 32*j;
      z[bt*DM+d] = zv[j];
      at[d][r] = zv[j]*rinv*rmsw[d];
    }
  }
  __syncthreads();
  float acc0[8], acc1[8];
  #pragma unroll
  for (int r=0;r<8;r++){ acc0[r]=0.f; acc1[r]=0.f; }
  int c0 = tid, c1 = tid+256;
  for (int k=0;k<128;k+=4){
    float4 w0v = *(const float4*)(W + c0*128 + k);
    float4 w1v = *(const float4*)(W + c1*128 + k);
    float w0[4] = {w0v.x, w0v.y, w0v.z, w0v.w};
    float w1[4] = {w1v.x, w1v.y, w1v.z, w1v.w};
    #pragma unroll
    for (int kk=0;kk<4;kk++){
      float a[8];
      *(float4*)&a[0] = *(const float4*)&at[k+kk][0];
      *(float4*)&a[4] = *(const float4*)&at[k+kk][4];
      #pragma unroll
      for (int r=0;r<8;r++){ acc0[r] = fmaf(a[r], w0[kk], acc0[r]); acc1[r] = fmaf(a[r], w1[kk], acc1[r]); }
    }
  }
  #pragma unroll
  for (int r=0;r<8;r++){
    int bt = bt0+r;
    xsr[bt*ED_ + c0] = acc0[r];
    zg [bt*ED_ + c0] = acc1[r];
  }
}

// K4b: staging computes conv(k=4)+bias+SiLU from xsr into LDS (and coalesced xs),
// then GEMM vs Wc: cols 0..255 -> delta=softplus(.+dt_b) [bt][e] coalesced;
// cols 256..319 -> B into BC[bt][n][0]; cols 320..383 -> C into BC[bt][n][1].
__global__ __launch_bounds__(384) void k4b_xproj(const float* xsr, const float* convW, const float* convb,
                                                 const float* Wc, const float* dtb,
                                                 float* xs, float* delta, float* BC){
  __shared__ float at[256][8];
  int bt0 = blockIdx.x*8; int tid = threadIdx.x;
  for (int i=tid;i<2048;i+=384){
    int r=i>>8,k=i&255; int bt=bt0+r; int t = bt & (T_SEQ-1);
    float4 wv = *(const float4*)(convW + k*4);
    float s = convb[k];
    if (t>=3) s += xsr[(bt-3)*ED_+k]*wv.x;
    if (t>=2) s += xsr[(bt-2)*ED_+k]*wv.y;
    if (t>=1) s += xsr[(bt-1)*ED_+k]*wv.z;
    s += xsr[bt*ED_+k]*wv.w;
    float v = s * sigmoidf_(s);
    at[k][r] = v;
    xs[bt*ED_+k] = v;
  }
  __syncthreads();
  float acc[8];
  #pragma unroll
  for (int r=0;r<8;r++) acc[r]=0.f;
  int c = tid;
  for (int k=0;k<256;k+=4){
    float4 wv = *(const float4*)(Wc + c*256 + k);
    float w[4] = {wv.x, wv.y, wv.z, wv.w};
    #pragma unroll
    for (int kk=0;kk<4;kk++){
      float a[8];
      *(float4*)&a[0] = *(const float4*)&at[k+kk][0];
      *(float4*)&a[4] = *(const float4*)&at[k+kk][4];
      #pragma unroll
      for (int r=0;r<8;r++) acc[r] = fmaf(a[r], w[kk], acc[r]);
    }
  }
  if (c < 256){
    float bc = dtb[c];
    #pragma unroll
    for (int r=0;r<8;r++){
      float x = acc[r] + bc;
      delta[(bt0+r)*ED_ + c] = (x > 20.f) ? x : log1pf(__expf(x));
    }
  } else if (c < 320){
    int n = c-256;
    #pragma unroll
    for (int r=0;r<8;r++) BC[((size_t)(bt0+r)*NS + n)*2]     = acc[r];
  } else {
    int n = c-320;
    #pragma unroll
    for (int r=0;r<8;r++) BC[((size_t)(bt0+r)*NS + n)*2 + 1] = acc[r];
  }
}

// K5a: per-chunk local scan (seed 0). Wave (b,e,c); lane n = state.
// delta/x for the wave's 64 t live in ONE register each (lane t holds t's value);
// per-t scalars come from v_readlane (no memory in the t-loop except BC dwordx2).
__global__ __launch_bounds__(256) void k5a_chunk(const float* __restrict__ delta, const float* __restrict__ xs,
                                                  const float* __restrict__ BC, const float* __restrict__ Alog,
                                                  float* __restrict__ S, float* __restrict__ sd_out){
  int w = threadIdx.x >> 6, n = threadIdx.x & 63;
  int b, c, e; scan_map(blockIdx.x, w, b, c, e);
  float A = -__expf(Alog[e*NS+n]);
  int base = b*T_SEQ + c*CLEN;
  const float* pd = delta + (size_t)base*ED_ + e;
  const float* px = xs    + (size_t)base*ED_ + e;
  const float2* pbc = (const float2*)BC + (size_t)base*NS + n;
  float dl_lane = pd[n*ED_];          // lane t -> delta[t]
  float xx_lane = px[n*ED_];          // lane t -> x[t]
  float dlxx = dl_lane * xx_lane;
  float h = 0.f;
  float2 bc[8], nbc[8];
  #pragma unroll
  for (int j=0;j<8;j++) bc[j] = pbc[j*NS];
  for (int t=0; t<CLEN; t+=8){
    if (t+8 < CLEN){
      #pragma unroll
      for (int j=0;j<8;j++) nbc[j] = pbc[(t+8+j)*NS];
    }
    #pragma unroll
    for (int j=0;j<8;j++){
      float sdl = rlane(dl_lane, t+j);
      float sq  = rlane(dlxx,   t+j);
      float a = __expf(sdl*A);
      h = fmaf(a, h, sq*bc[j].x);
    }
    #pragma unroll
    for (int j=0;j<8;j++) bc[j] = nbc[j];
  }
  float sd = dl_lane;                 // wave sum of delta -> lane 63
  DPP_L1(sd); DPP_L2(sd); DPP_L3(sd); DPP_L4(sd); DPP_L5(sd); DPP_L6(sd);
  int g = (b*ED_+e)*NCHUNK + c;
  S[(size_t)g*NS+n] = h;
  if (n==63) sd_out[g] = sd;
}

// K5c: prologue folds chunks 0..c-1 into seed h; t-loop identical to k5a plus
// p = h*C and 8 interleaved single-instruction DPP reduce chains; lane 63
// stores raw p[t].
__global__ __launch_bounds__(256) void k5c_scan(const float* __restrict__ delta, const float* __restrict__ xs,
                                                 const float* __restrict__ BC, const float* __restrict__ Alog,
                                                 const float* __restrict__ S, const float* __restrict__ sd_in,
                                                 float* __restrict__ yr){
  int w = threadIdx.x >> 6, n = threadIdx.x & 63;
  int b, c, e; scan_map(blockIdx.x, w, b, c, e);
  float A = -__expf(Alog[e*NS+n]);
  int gbase = (b*ED_+e)*NCHUNK;
  float h = 0.f;
  for (int cc=0; cc<c; ++cc){         // c is block-uniform -> no divergence
    float p = __expf(sd_in[gbase+cc]*A);
    h = fmaf(p, h, S[(size_t)(gbase+cc)*NS+n]);
  }
  int base = b*T_SEQ + c*CLEN;
  const float* pd = delta + (size_t)base*ED_ + e;
  const float* px = xs    + (size_t)base*ED_ + e;
  const float2* pbc = (const float2*)BC + (size_t)base*NS + n;
  float*        py  = yr + (size_t)base*ED_ + e;
  float dl_lane = pd[n*ED_];
  float xx_lane = px[n*ED_];
  float dlxx = dl_lane * xx_lane;
  bool last = (n==63);
  float2 bc[8], nbc[8];
  #pragma unroll
  for (int j=0;j<8;j++) bc[j] = pbc[j*NS];
  for (int t=0; t<CLEN; t+=8){
    if (t+8 < CLEN){
      #pragma unroll
      for (int j=0;j<8;j++) nbc[j] = pbc[(t+8+j)*NS];
    }
    float pp[8];
    #pragma unroll
    for (int j=0;j<8;j++){
      float sdl = rlane(dl_lane, t+j);
      float sq  = rlane(dlxx,   t+j);
      float a = __expf(sdl*A);
      h = fmaf(a, h, sq*bc[j].x);
      pp[j] = h*bc[j].y;
    }
    #pragma unroll
    for (int j=0;j<8;j++) DPP_L1(pp[j]);
    #pragma unroll
    for (int j=0;j<8;j++) DPP_L2(pp[j]);
    #pragma unroll
    for (int j=0;j<8;j++) DPP_L3(pp[j]);
    #pragma unroll
    for (int j=0;j<8;j++) DPP_L4(pp[j]);
    #pragma unroll
    for (int j=0;j<8;j++) DPP_L5(pp[j]);
    #pragma unroll
    for (int j=0;j<8;j++) DPP_L6(pp[j]);
    if (last){
      #pragma unroll
      for (int j=0;j<8;j++) py[(t+j)*ED_] = pp[j];
    }
    #pragma unroll
    for (int j=0;j<8;j++) bc[j] = nbc[j];
  }
}

// K6: y = (yr + D*xs)*silu(zg);  out = LayerNorm(y @ out_proj_W.T + 2*z)*ln_w + ln_b
__global__ __launch_bounds__(256) void k6_out(const float* yr, const float* xs, const float* zg,
                                               const float* Dp, const float* W, const float* z,
                                               const float* lnw, const float* lnb, float* out){
  __shared__ float yt[256][8];
  __shared__ float psum[4][4], psq[4][4];
  int bt0 = blockIdx.x*8; int tid = threadIdx.x;
  int d = tid & 127, gdx = tid>>7;
  for (int i=tid;i<2048;i+=256){
    int r=i>>8,k=i&255; int bt=bt0+r;
    float zgv = zg[bt*ED_ + k];
    float yv  = yr[bt*ED_ + k] + Dp[k]*xs[bt*ED_ + k];
    yt[k][r] = yv * zgv * sigmoidf_(zgv);
  }
  __syncthreads();
  float acc[4] = {0.f,0.f,0.f,0.f};
  for (int k=0;k<256;k+=4){
    float4 wv = *(const float4*)(W + d*256 + k);
    float w[4] = {wv.x, wv.y, wv.z, wv.w};
    #pragma unroll
    for (int kk=0;kk<4;kk++){
      float4 q = *(const float4*)&yt[k+kk][gdx*4];
      acc[0] = fmaf(q.x, w[kk], acc[0]);
      acc[1] = fmaf(q.y, w[kk], acc[1]);
      acc[2] = fmaf(q.z, w[kk], acc[2]);
      acc[3] = fmaf(q.w, w[kk], acc[3]);
    }
  }
  float val[4];
  #pragma unroll
  for (int j=0;j<4;j++){
    int bt = bt0 + gdx*4 + j;
    val[j] = acc[j] + 2.f*z[bt*DM + d];
  }
  int w_id = tid>>6;
  #pragma unroll
  for (int j=0;j<4;j++){
    float s = val[j], q = val[j]*val[j];
    #pragma unroll
    for (int off=32; off>=1; off>>=1){ s += __shfl_down(s, off); q += __shfl_down(q, off); }
    if ((tid&63)==0){ psum[w_id][j]=s; psq[w_id][j]=q; }
  }
  __syncthreads();
  float lw = lnw[d], lb = lnb[d];
  #pragma unroll
  for (int j=0;j<4;j++){
    int bt = bt0 + gdx*4 + j;
    float sum = psum[gdx*2][j] + psum[gdx*2+1][j];
    float sq  = psq [gdx*2][j] + psq [gdx*2+1][j];
    float mu  = sum*(1.f/DM);
    float var = sq*(1.f/DM) - mu*mu;
    float inv = rsqrtf(var + 1e-5f);
    out[bt*DM + d] = (val[j]-mu)*inv*lw + lb;
  }
}

extern "C" void kernel_launch(void* const* d_in, const int* in_sizes, int n_in,
                              void* d_out, int out_size, void* d_ws, size_t ws_size,
                              hipStream_t stream){
  const float* zseq = (const float*)d_in[0];
  const float* aux  = (const float*)d_in[1];
  const float* auxW = (const float*)d_in[2];
  const float* auxb = (const float*)d_in[3];
  const float* lnw  = (const float*)d_in[4];
  const float* lnb  = (const float*)d_in[5];
  const float* rmsw = (const float*)d_in[6];
  const float* inW  = (const float*)d_in[7];
  const float* convW= (const float*)d_in[8];
  const float* convb= (const float*)d_in[9];
  const float* xpW  = (const float*)d_in[10];
  const float* dtW  = (const float*)d_in[11];
  const float* dtb  = (const float*)d_in[12];
  const float* Alog = (const float*)d_in[13];
  const float* Dp   = (const float*)d_in[14];
  const float* outW = (const float*)d_in[15];
  float* out = (float*)d_out;
  float* ws = (float*)d_ws;

  float* z   = ws+OFF_Z;
  float* BC  = ws+OFF_BC;
  float* xsr = ws+OFF_XSR;  float* zg = ws+OFF_ZG;   float* xs = ws+OFF_XS;
  float* Wc  = ws+OFF_WC;
  float* yr  = ws+OFF_YR;   float* dl = ws+OFF_DELTA;
  float* S   = ws+OFF_S;    float* sd = ws+OFF_SD;

  k2_fused <<<896,256,0,stream>>>(zseq,aux,auxW,auxb,rmsw,inW,xpW,dtW,z,xsr,zg,Wc);
  k4b_xproj<<<512,384,0,stream>>>(xsr,convW,convb,Wc,dtb,xs,dl,BC);
  k5a_chunk<<<4096,256,0,stream>>>(dl,xs,BC,Alog,S,sd);
  k5c_scan <<<4096,256,0,stream>>>(dl,xs,BC,Alog,S,sd,yr);
  k6_out   <<<512,256,0,stream>>>(yr,xs,zg,Dp,outW,z,lnw,lnb,out);
}